// Round 21
// baseline (284.850 us; speedup 1.0000x reference)
//
#include <hip/hip_runtime.h>

#define N_NODES 102
#define NP 8192          // pairs (B*n)
#define RB192 4352       // 192-row blocks (835584/192), = 128 * 34 exactly
#define GRIDX 128
#define NITER 34
#define XWIN 612         // 3 pairs * 204 floats per staging window

typedef _Float16 f16x8 __attribute__((ext_vector_type(8)));
typedef _Float16 f16x2 __attribute__((ext_vector_type(2)));
typedef float f32x4 __attribute__((ext_vector_type(4)));

// ---------------- Kernel 1: build sparse propagation tables ----------------------
__global__ void build_tables(const int* __restrict__ ei, int ne,
                             int4* __restrict__ gtu, float4* __restrict__ gtw) {
    __shared__ int   deg[N_NODES];
    __shared__ float dinv[N_NODES];
    __shared__ int   cnt[N_NODES];
    __shared__ int   tu[N_NODES][4];
    __shared__ float tw[N_NODES][4];
    int t = threadIdx.x;
    if (t < N_NODES) deg[t] = 1;                       // self-loop
    __syncthreads();
    if (t == 0) for (int e = 0; e < ne; ++e) deg[ei[ne + e]] += 1;
    __syncthreads();
    if (t < N_NODES) {
        dinv[t] = 1.0f / sqrtf((float)deg[t]);
        cnt[t] = 1;
        for (int j = 0; j < 4; ++j) { tu[t][j] = 2 * t; tw[t][j] = 0.0f; }
    }
    __syncthreads();
    if (t < N_NODES) tw[t][0] = dinv[t] * dinv[t];     // diagonal self-loop
    __syncthreads();
    if (t == 0) {
        for (int e = 0; e < ne; ++e) {
            int r = ei[e], c = ei[ne + e];
            int s = cnt[c] < 4 ? cnt[c] : 3;           // clamp (never hit here)
            cnt[c] = s + 1;
            tu[c][s] = 2 * r;
            tw[c][s] = dinv[r] * dinv[c];
        }
    }
    __syncthreads();
    if (t < N_NODES) {
        gtu[t] = make_int4(tu[t][0], tu[t][1], tu[t][2], tu[t][3]);
        gtw[t] = make_float4(tw[t][0], tw[t][1], tw[t][2], tw[t][3]);
    }
}

// ---------------- Kernel 1b: WpT[col][k] = (f16)Wp[k][col] (proven in R13) -------
__global__ void prep_w(const float* __restrict__ Wp, _Float16* __restrict__ WpT) {
    int tid = blockIdx.x * 256 + threadIdx.x;          // 64 x 256 = 16384
    for (int i = tid; i < 65536; i += 16384) {         // i = k*256 + col (coalesced)
        int col = i & 255, k = i >> 8;
        WpT[col * 256 + k] = (_Float16)Wp[i];
    }
}

// ---------------- Kernel 2: persistent GNN, producer/consumer waves --------------
// R15 core re-roled: waves 0-2 = consumers (192-row tile, reg-resident bfragR,
// LDS-only inputs, fire-and-forget stores, NO vmcnt waits ever); wave 3 =
// producer (global x loads -> ping-pong LDS xs; its vmcnt queue has only loads).
// One raw s_barrier per iteration publishes the next window. Stores stream.
__global__ __launch_bounds__(256, 2) void gnn_main(
    const float* __restrict__ x,       // [NP][204] fp32
    const _Float16* __restrict__ WpT,  // [256 col][256 k] f16
    const int4*  __restrict__ gtu,     // [102]
    const float4* __restrict__ gtw,    // [102]
    const float* __restrict__ Wg,      // [2][256]
    const float* __restrict__ bg,      // [256]
    const float* __restrict__ bp,      // [256]
    float* __restrict__ out)           // [R][256]
{
    __shared__ float xsb[2][XWIN];     // ping-pong x windows (2 x 2.45 KB)
    __shared__ int4   stu[N_NODES];
    __shared__ float4 stw[N_NODES];
    __shared__ _Float16 W0l[256], W1l[256], bgl[256];
    const int tid = threadIdx.x;
    const int w  = tid >> 6;
    const int l  = tid & 63;
    const int qk = l >> 4;
    const int m  = l & 15;
    const int c0  = blockIdx.y * 64;
    const int rbi = blockIdx.x;
    const size_t gmax = (size_t)NP * (2 * N_NODES);

    // Consumers hoist B fragments into registers (L2-resident WpT)
    f16x8 bfragR[8][4];
    if (w < 3) {
        #pragma unroll
        for (int t = 0; t < 8; ++t)
            #pragma unroll
            for (int nt = 0; nt < 4; ++nt)
                bfragR[t][nt] = *reinterpret_cast<const f16x8*>(
                    &WpT[(c0 + nt * 16 + m) * 256 + qk * 8 + 32 * t]);
    }

    // Stage tables + GNN weights (once)
    if (tid < N_NODES) { stu[tid] = gtu[tid]; stw[tid] = gtw[tid]; }
    W0l[tid] = (_Float16)Wg[tid];
    W1l[tid] = (_Float16)Wg[256 + tid];
    bgl[tid] = (_Float16)bg[tid];

    float bpf[4];
    #pragma unroll
    for (int nt = 0; nt < 4; ++nt) bpf[nt] = bp[c0 + nt * 16 + m];

    // Prologue: producer stages window for iteration 0 into xsb[0]
    if (w == 3) {
        const int pb0 = (rbi * 192) / N_NODES;
        const size_t gbase = (size_t)pb0 * (2 * N_NODES);
        #pragma unroll
        for (int i = 0; i < 10; ++i) {
            int idx = l + i * 64;
            if (idx < XWIN)
                xsb[0][idx] = (gbase + idx < gmax) ? x[gbase + idx] : 0.0f;
        }
    }
    __syncthreads();   // full drain once; xsb[0] published

    const f16x2 z2 = (f16x2){ (_Float16)0.0f, (_Float16)0.0f };

    #pragma unroll 1
    for (int j = 0; j < NITER; ++j) {
        const int rb = rbi + j * GRIDX;            // < 4352 always (zero tail)
        const int cur = j & 1;

        if (w < 3) {
            // ---------------- consumer: LDS-only inputs, streaming stores -------
            const int rowblk = rb * 192;
            const int pbase  = rowblk / N_NODES;
            const float* xsw = xsb[cur];

            f16x2 y0pk[4], y1pk[4];
            #pragma unroll
            for (int s = 0; s < 4; ++s) {
                int r = rowblk + w * 64 + s * 16 + m;
                int p = r / N_NODES;
                int v = r - p * N_NODES;
                const float* xp = &xsw[(p - pbase) * 2 * N_NODES];
                int4  U = stu[v];
                float4 W = stw[v];
                float a0 = W.x * xp[U.x]     + W.y * xp[U.y]
                         + W.z * xp[U.z]     + W.w * xp[U.w];
                float a1 = W.x * xp[U.x + 1] + W.y * xp[U.y + 1]
                         + W.z * xp[U.z + 1] + W.w * xp[U.w + 1];
                _Float16 h0 = (_Float16)a0;
                _Float16 h1 = (_Float16)a1;
                y0pk[s] = (f16x2){ h0, h0 };
                y1pk[s] = (f16x2){ h1, h1 };
            }

            f32x4 acc[4][4];
            #pragma unroll
            for (int s = 0; s < 4; ++s)
                #pragma unroll
                for (int nt = 0; nt < 4; ++nt)
                    acc[s][nt] = (f32x4){0.f, 0.f, 0.f, 0.f};

            #pragma unroll
            for (int t = 0; t < 8; ++t) {
                const int kk = qk * 8 + 32 * t;
                union { f16x8 v; f16x2 p[4]; } w0u, w1u, bbu;
                w0u.v = *reinterpret_cast<const f16x8*>(&W0l[kk]);
                w1u.v = *reinterpret_cast<const f16x8*>(&W1l[kk]);
                bbu.v = *reinterpret_cast<const f16x8*>(&bgl[kk]);
                #pragma unroll
                for (int s = 0; s < 4; ++s) {
                    union { f16x8 v; f16x2 p[4]; } af;
                    #pragma unroll
                    for (int j2 = 0; j2 < 4; ++j2) {
                        f16x2 h = w0u.p[j2] * y0pk[s] + w1u.p[j2] * y1pk[s] + bbu.p[j2];
                        af.p[j2] = __builtin_elementwise_max(h, z2);
                    }
                    #pragma unroll
                    for (int nt = 0; nt < 4; ++nt)
                        acc[s][nt] = __builtin_amdgcn_mfma_f32_16x16x32_f16(af.v, bfragR[t][nt], acc[s][nt], 0, 0, 0);
                }
            }

            // Fire-and-forget scalar stores (never awaited in-loop)
            const long rowbase = (long)rowblk + (long)w * 64;
            #pragma unroll
            for (int s = 0; s < 4; ++s) {
                #pragma unroll
                for (int nt = 0; nt < 4; ++nt) {
                    const int e = c0 + nt * 16 + m;
                    #pragma unroll
                    for (int reg = 0; reg < 4; ++reg) {
                        long r = rowbase + s * 16 + qk * 4 + reg;
                        out[r * 256 + e] = acc[s][nt][reg] + bpf[nt];
                    }
                }
            }
        } else {
            // ---------------- producer: stage next window (loads-only queue) ----
            if (j + 1 < NITER) {
                const int rbn = rbi + (j + 1) * GRIDX;
                const int pbn = (rbn * 192) / N_NODES;
                const size_t gbase = (size_t)pbn * (2 * N_NODES);
                float tmp[10];
                #pragma unroll
                for (int i = 0; i < 10; ++i) {
                    int idx = l + i * 64;
                    tmp[i] = (idx < XWIN && gbase + idx < gmax) ? x[gbase + idx] : 0.0f;
                }
                float* dst = xsb[cur ^ 1];
                #pragma unroll
                for (int i = 0; i < 10; ++i) {
                    int idx = l + i * 64;
                    if (idx < XWIN) dst[idx] = tmp[i];
                }
            }
            asm volatile("s_waitcnt lgkmcnt(0)" ::: "memory");   // ds_writes visible
        }

        __builtin_amdgcn_s_barrier();          // publish window (no vmcnt drain)
        asm volatile("" ::: "memory");         // block LDS motion across barrier
    }
}

extern "C" void kernel_launch(void* const* d_in, const int* in_sizes, int n_in,
                              void* d_out, int out_size, void* d_ws, size_t ws_size,
                              hipStream_t stream) {
    const float* x  = (const float*)d_in[0];
    const float* Wg = (const float*)d_in[1];
    const float* bg = (const float*)d_in[2];
    const float* Wp = (const float*)d_in[3];
    const float* bp = (const float*)d_in[4];
    const int* ei   = (const int*)d_in[5];
    float* out = (float*)d_out;

    const int ne = in_sizes[5] / 2;                 // 84

    int4*     gtu = (int4*)d_ws;                        // 102 int4
    float4*   gtw = (float4*)((char*)d_ws + 2048);      // 102 float4
    _Float16* WpT = (_Float16*)((char*)d_ws + 4096);    // 65536 f16 = 128 KB

    build_tables<<<1, 128, 0, stream>>>(ei, ne, gtu, gtw);
    prep_w<<<64, 256, 0, stream>>>(Wp, WpT);

    gnn_main<<<dim3(GRIDX, 4), 256, 0, stream>>>(x, WpT, gtu, gtw, Wg, bg, bp, out);
}

// Round 22
// 203.356 us; speedup vs baseline: 1.4007x; 1.4007x over previous
//
#include <hip/hip_runtime.h>

#define N_NODES 102
#define NP 8192          // pairs (B*n)
#define RBLOCKS 3264     // 256-row blocks
#define RSTRIDE 128      // persistent grid x-dim

typedef _Float16 f16x8 __attribute__((ext_vector_type(8)));
typedef _Float16 f16x2 __attribute__((ext_vector_type(2)));
typedef float f32x4 __attribute__((ext_vector_type(4)));

#define GLOAD_LDS16(src, dst) \
    __builtin_amdgcn_global_load_lds((const __attribute__((address_space(1))) void*)(src), \
                                     (__attribute__((address_space(3))) void*)(dst), 16, 0, 0)

// ---------------- Kernel 1: build sparse propagation tables ----------------------
__global__ void build_tables(const int* __restrict__ ei, int ne,
                             int4* __restrict__ gtu, float4* __restrict__ gtw) {
    __shared__ int   deg[N_NODES];
    __shared__ float dinv[N_NODES];
    __shared__ int   cnt[N_NODES];
    __shared__ int   tu[N_NODES][4];
    __shared__ float tw[N_NODES][4];
    int t = threadIdx.x;
    if (t < N_NODES) deg[t] = 1;                       // self-loop
    __syncthreads();
    if (t == 0) for (int e = 0; e < ne; ++e) deg[ei[ne + e]] += 1;
    __syncthreads();
    if (t < N_NODES) {
        dinv[t] = 1.0f / sqrtf((float)deg[t]);
        cnt[t] = 1;
        for (int j = 0; j < 4; ++j) { tu[t][j] = 2 * t; tw[t][j] = 0.0f; }
    }
    __syncthreads();
    if (t < N_NODES) tw[t][0] = dinv[t] * dinv[t];     // diagonal self-loop
    __syncthreads();
    if (t == 0) {
        for (int e = 0; e < ne; ++e) {
            int r = ei[e], c = ei[ne + e];
            int s = cnt[c] < 4 ? cnt[c] : 3;           // clamp (never hit here)
            cnt[c] = s + 1;
            tu[c][s] = 2 * r;
            tw[c][s] = dinv[r] * dinv[c];
        }
    }
    __syncthreads();
    if (t < N_NODES) {
        gtu[t] = make_int4(tu[t][0], tu[t][1], tu[t][2], tu[t][3]);
        gtw[t] = make_float4(tw[t][0], tw[t][1], tw[t][2], tw[t][3]);
    }
}

// ---------------- Kernel 1b: WpT[col][k] = (f16)Wp[k][col] (proven in R13) -------
__global__ void prep_w(const float* __restrict__ Wp, _Float16* __restrict__ WpT) {
    int tid = blockIdx.x * 256 + threadIdx.x;          // 64 x 256 = 16384
    for (int i = tid; i < 65536; i += 16384) {         // i = k*256 + col (coalesced)
        int col = i & 255, k = i >> 8;
        WpT[col * 256 + k] = (_Float16)Wp[i];
    }
}

// ---------------- Kernel 2: persistent fused GNN, vmcnt-ordered prefetch ---------
// R15-verbatim EXCEPT: xs staged via ONE global_load_lds per wave per iteration
// (wave w stages pair pbase+w, 51 lanes x 16B, linear dest, ping-pong buffer),
// issued BEFORE the 64 epilogue stores. At next iteration top, vmcnt(63)
// (in-order retire) guarantees the load done while ~63 stores stay in flight
// under this iteration's compute. Raw s_barrier (no vmcnt(0) drain).
__global__ __launch_bounds__(256, 2) void gnn_main(
    const float* __restrict__ x,       // [NP][204] fp32
    const _Float16* __restrict__ WpT,  // [256 col][256 k] f16
    const int4*  __restrict__ gtu,     // [102]
    const float4* __restrict__ gtw,    // [102]
    const float* __restrict__ Wg,      // [2][256]
    const float* __restrict__ bg,      // [256]
    const float* __restrict__ bp,      // [256]
    float* __restrict__ out)           // [R][256]
{
    __shared__ float xsb[2][4 * 2 * N_NODES];   // ping-pong 2 x 3264B
    __shared__ int4   stu[N_NODES];
    __shared__ float4 stw[N_NODES];
    __shared__ _Float16 W0l[256], W1l[256], bgl[256];
    const int tid = threadIdx.x;
    const int w  = tid >> 6;
    const int l  = tid & 63;
    const int qk = l >> 4;
    const int m  = l & 15;
    const int c0  = blockIdx.y * 64;
    const int rbi = blockIdx.x;

    // Hoist all B fragments into registers (32 x 16B, L2-resident WpT)
    f16x8 bfragR[8][4];
    #pragma unroll
    for (int t = 0; t < 8; ++t)
        #pragma unroll
        for (int nt = 0; nt < 4; ++nt)
            bfragR[t][nt] = *reinterpret_cast<const f16x8*>(
                &WpT[(c0 + nt * 16 + m) * 256 + qk * 8 + 32 * t]);

    // Stage tables + GNN weights (once)
    if (tid < N_NODES) { stu[tid] = gtu[tid]; stw[tid] = gtw[tid]; }
    W0l[tid] = (_Float16)Wg[tid];
    W1l[tid] = (_Float16)Wg[256 + tid];
    bgl[tid] = (_Float16)bg[tid];

    float bpf[4];
    #pragma unroll
    for (int nt = 0; nt < 4; ++nt) bpf[nt] = bp[c0 + nt * 16 + m];

    // Prologue: stage iter-0 window into xsb[0] (wave w -> pair pbase+w)
    {
        const int pb0 = (rbi * 256) / N_NODES;
        if (pb0 + w < NP && l < 51)
            GLOAD_LDS16(x + (size_t)(pb0 + w) * (2 * N_NODES) + l * 4,
                        &xsb[0][w * (2 * N_NODES)]);
    }
    __syncthreads();   // full drain once; xsb[0] published

    const f16x2 z2 = (f16x2){ (_Float16)0.0f, (_Float16)0.0f };

    #pragma unroll 1
    for (int j = 0; j < 26; ++j) {
        const int rb = rbi + j * RSTRIDE;
        if (rb >= RBLOCKS) break;
        const int rowblk = rb * 256;
        const int pbase  = rowblk / N_NODES;
        const int cur = j & 1;

        // In-order vmcnt: my prefetch load (oldest) retired; ~63 stores stay in flight
        asm volatile("s_waitcnt vmcnt(63)" ::: "memory");
        __builtin_amdgcn_s_barrier();          // publish xsb[cur] (no vmcnt(0) drain)
        __builtin_amdgcn_sched_barrier(0);

        // Prefetch NEXT window into xsb[cur^1] — issued BEFORE this iter's stores
        {
            const int rbn = rbi + (j + 1) * RSTRIDE;
            if (rbn < RBLOCKS) {
                const int pbn = (rbn * 256) / N_NODES;
                if (pbn + w < NP && l < 51)
                    GLOAD_LDS16(x + (size_t)(pbn + w) * (2 * N_NODES) + l * 4,
                                &xsb[cur ^ 1][w * (2 * N_NODES)]);
            }
        }

        // y-gen from sparse tables (R15-verbatim, reads xsb[cur])
        const float* xsw = xsb[cur];
        f16x2 y0pk[4], y1pk[4];
        #pragma unroll
        for (int s = 0; s < 4; ++s) {
            int r = rowblk + w * 64 + s * 16 + m;
            int p = r / N_NODES;
            int v = r - p * N_NODES;
            const float* xp = &xsw[(p - pbase) * 2 * N_NODES];
            int4  U = stu[v];
            float4 W = stw[v];
            float a0 = W.x * xp[U.x]     + W.y * xp[U.y]
                     + W.z * xp[U.z]     + W.w * xp[U.w];
            float a1 = W.x * xp[U.x + 1] + W.y * xp[U.y + 1]
                     + W.z * xp[U.z + 1] + W.w * xp[U.w + 1];
            _Float16 h0 = (_Float16)a0;
            _Float16 h1 = (_Float16)a1;
            y0pk[s] = (f16x2){ h0, h0 };
            y1pk[s] = (f16x2){ h1, h1 };
        }

        f32x4 acc[4][4];
        #pragma unroll
        for (int s = 0; s < 4; ++s)
            #pragma unroll
            for (int nt = 0; nt < 4; ++nt)
                acc[s][nt] = (f32x4){0.f, 0.f, 0.f, 0.f};

        #pragma unroll
        for (int t = 0; t < 8; ++t) {
            const int kk = qk * 8 + 32 * t;
            union { f16x8 v; f16x2 p[4]; } w0u, w1u, bbu;
            w0u.v = *reinterpret_cast<const f16x8*>(&W0l[kk]);
            w1u.v = *reinterpret_cast<const f16x8*>(&W1l[kk]);
            bbu.v = *reinterpret_cast<const f16x8*>(&bgl[kk]);
            #pragma unroll
            for (int s = 0; s < 4; ++s) {
                union { f16x8 v; f16x2 p[4]; } af;
                #pragma unroll
                for (int j2 = 0; j2 < 4; ++j2) {
                    f16x2 h = w0u.p[j2] * y0pk[s] + w1u.p[j2] * y1pk[s] + bbu.p[j2];
                    af.p[j2] = __builtin_elementwise_max(h, z2);
                }
                #pragma unroll
                for (int nt = 0; nt < 4; ++nt)
                    acc[s][nt] = __builtin_amdgcn_mfma_f32_16x16x32_f16(af.v, bfragR[t][nt], acc[s][nt], 0, 0, 0);
            }
        }

        // Epilogue: + b_proj, scalar stores (R15-verbatim; fire-and-forget)
        const long rowbase = (long)rowblk + (long)w * 64;
        #pragma unroll
        for (int s = 0; s < 4; ++s) {
            #pragma unroll
            for (int nt = 0; nt < 4; ++nt) {
                const int e = c0 + nt * 16 + m;
                #pragma unroll
                for (int reg = 0; reg < 4; ++reg) {
                    long r = rowbase + s * 16 + qk * 4 + reg;
                    out[r * 256 + e] = acc[s][nt][reg] + bpf[nt];
                }
            }
        }
    }
}

extern "C" void kernel_launch(void* const* d_in, const int* in_sizes, int n_in,
                              void* d_out, int out_size, void* d_ws, size_t ws_size,
                              hipStream_t stream) {
    const float* x  = (const float*)d_in[0];
    const float* Wg = (const float*)d_in[1];
    const float* bg = (const float*)d_in[2];
    const float* Wp = (const float*)d_in[3];
    const float* bp = (const float*)d_in[4];
    const int* ei   = (const int*)d_in[5];
    float* out = (float*)d_out;

    const int ne = in_sizes[5] / 2;                 // 84

    int4*     gtu = (int4*)d_ws;                        // 102 int4
    float4*   gtw = (float4*)((char*)d_ws + 2048);      // 102 float4
    _Float16* WpT = (_Float16*)((char*)d_ws + 4096);    // 65536 f16 = 128 KB

    build_tables<<<1, 128, 0, stream>>>(ei, ne, gtu, gtw);
    prep_w<<<64, 256, 0, stream>>>(Wp, WpT);

    gnn_main<<<dim3(RSTRIDE, 4), 256, 0, stream>>>(x, WpT, gtu, gtw, Wg, bg, bp, out);
}